// Round 1
// baseline (87.178 us; speedup 1.0000x reference)
//
#include <hip/hip_runtime.h>

// DirectMaskedProjection: H=W=128, D=64, HIDDEN=64, mask vol 128^3 fp32.
// One thread per sample point; one wave (64 lanes) == one pixel's depth column.
// Inputs (fp32): [0] transform [1,4,4], [1] mask_vol [128^3],
//                [2] W1 [3,64], [3] b1 [64], [4] W2 [64,1], [5] b2 [1]
// Output: fp32 [1,128,128] = 16384 elements.

#define NH 128
#define NW 128
#define ND 64
#define HID 64

__global__ __launch_bounds__(256) void dmp_kernel(
    const float* __restrict__ T,    // [16]
    const float* __restrict__ vol,  // [128,128,128] (z,y,x)
    const float* __restrict__ W1,   // [3,64] row-major
    const float* __restrict__ b1,   // [64]
    const float* __restrict__ W2,   // [64]
    const float* __restrict__ b2,   // [1]
    float* __restrict__ out)        // [128*128]
{
    const int t   = blockIdx.x * 256 + threadIdx.x;   // point index
    const int d   = t & 63;                           // depth sample == lane
    const int pix = t >> 6;                           // pixel index h*128+w
    const int h   = pix >> 7;
    const int w   = pix & 127;

    // centered base grid (center_grid_origin): x=h-63.5, y=w-63.5, z=(d-31.5)*2
    const float bx = (float)h - 63.5f;
    const float by = (float)w - 63.5f;
    const float bz = ((float)d - 31.5f) * 2.0f;

    // q = T @ [bx,by,bz,1]  (T uniform across threads -> scalar loads)
    const float q0 = T[0]  * bx + T[1]  * by + T[2]  * bz + T[3];
    const float q1 = T[4]  * bx + T[5]  * by + T[6]  * bz + T[7];
    const float q2 = T[8]  * bx + T[9]  * by + T[10] * bz + T[11];
    const float qw = T[12] * bx + T[13] * by + T[14] * bz + T[15];

    // normalize by max|base coord| = 63.5
    const float inv_max = 1.0f / 63.5f;
    const float nx = q0 * inv_max;
    const float ny = q1 * inv_max;
    const float nz = q2 * inv_max;

    // trilinear sample, align_corners=True, padding zeros.
    // vol dims [Dm,Hm,Wm] = [128,128,128]; x->Wm, y->Hm, z->Dm.
    const float xf = (nx + 1.0f) * 0.5f * 127.0f;
    const float yf = (ny + 1.0f) * 0.5f * 127.0f;
    const float zf = (nz + 1.0f) * 0.5f * 127.0f;
    const float x0 = floorf(xf), y0 = floorf(yf), z0 = floorf(zf);
    const float fx = xf - x0, fy = yf - y0, fz = zf - z0;

    float m = 0.0f;
    #pragma unroll
    for (int dz_ = 0; dz_ < 2; ++dz_) {
        #pragma unroll
        for (int dy_ = 0; dy_ < 2; ++dy_) {
            #pragma unroll
            for (int dx_ = 0; dx_ < 2; ++dx_) {
                const float xi = x0 + (float)dx_;
                const float yi = y0 + (float)dy_;
                const float zi = z0 + (float)dz_;
                const float wgt = (dx_ ? fx : 1.0f - fx)
                                * (dy_ ? fy : 1.0f - fy)
                                * (dz_ ? fz : 1.0f - fz);
                const bool valid = (xi >= 0.0f) && (xi <= 127.0f)
                                && (yi >= 0.0f) && (yi <= 127.0f)
                                && (zi >= 0.0f) && (zi <= 127.0f);
                const int xc = min(max((int)xi, 0), 127);
                const int yc = min(max((int)yi, 0), 127);
                const int zc = min(max((int)zi, 0), 127);
                const float v = vol[(zc * 128 + yc) * 128 + xc];
                m += wgt * (valid ? v : 0.0f);   // sum of non-negative terms
            }
        }
    }
    const float mask = (m != 0.0f) ? 1.0f : 0.0f;

    // field MLP: relu(q3 @ W1 + b1) @ W2 + b2, with q3 = q/qw (qw == 1)
    const float invw = 1.0f / qw;
    const float p0 = q0 * invw, p1 = q1 * invw, p2 = q2 * invw;
    float pot = b2[0];
    #pragma unroll 8
    for (int j = 0; j < HID; ++j) {
        float hj = p0 * W1[j] + p1 * W1[64 + j] + p2 * W1[128 + j] + b1[j];
        hj = fmaxf(hj, 0.0f);
        pot += hj * W2[j];
    }

    // per-pixel reduction over the 64 depth lanes (one full wave)
    float val = pot * mask;
    #pragma unroll
    for (int off = 32; off > 0; off >>= 1)
        val += __shfl_down(val, off);

    if (d == 0)
        out[pix] = val * 2.0f;   // * DZ
}

extern "C" void kernel_launch(void* const* d_in, const int* in_sizes, int n_in,
                              void* d_out, int out_size, void* d_ws, size_t ws_size,
                              hipStream_t stream) {
    const float* T   = (const float*)d_in[0];
    const float* vol = (const float*)d_in[1];
    const float* W1  = (const float*)d_in[2];
    const float* b1  = (const float*)d_in[3];
    const float* W2  = (const float*)d_in[4];
    const float* b2  = (const float*)d_in[5];
    float* out = (float*)d_out;

    const int n_points = NH * NW * ND;          // 1,048,576
    dmp_kernel<<<n_points / 256, 256, 0, stream>>>(T, vol, W1, b1, W2, b2, out);
}

// Round 2
// 86.769 us; speedup vs baseline: 1.0047x; 1.0047x over previous
//
#include <hip/hip_runtime.h>

// DirectMaskedProjection: H=W=128, D=64, HIDDEN=64, mask vol 128^3 fp32 (binary).
// Round 2: bit-pack the binary mask volume (8 MB -> 256 KB) into d_ws each
// launch, gather bits instead of floats. Numerics of m / mask / MLP identical
// to round 1 (which passed at absmax 1.0).
//
// Inputs (fp32): [0] transform [1,4,4], [1] mask_vol [128^3],
//                [2] W1 [3,64], [3] b1 [64], [4] W2 [64,1], [5] b2 [1]
// Output: fp32 [1,128,128] = 16384 elements.

#define NH 128
#define NW 128
#define ND 64
#define HID 64

// Pack vol!=0 into bits: voxel index t -> bit (t & 63) of word (t >> 6).
// x is the fastest-varying dim, so a wave's 64 lanes = 64 consecutive x.
__global__ __launch_bounds__(256) void pack_kernel(
    const float* __restrict__ vol,
    unsigned long long* __restrict__ bits)
{
    const int t = blockIdx.x * 256 + threadIdx.x;   // 2^21 voxels
    const float v = vol[t];
    const unsigned long long b = __ballot(v != 0.0f);
    if ((threadIdx.x & 63) == 0)
        bits[t >> 6] = b;
}

__global__ __launch_bounds__(256) void dmp_kernel(
    const float* __restrict__ T,          // [16]
    const unsigned int* __restrict__ bw,  // packed bits, 128*128*4 u32 words
    const float* __restrict__ W1,         // [3,64] row-major
    const float* __restrict__ b1,         // [64]
    const float* __restrict__ W2,         // [64]
    const float* __restrict__ b2,         // [1]
    float* __restrict__ out)              // [128*128]
{
    const int t   = blockIdx.x * 256 + threadIdx.x;   // point index
    const int d   = t & 63;                           // depth sample == lane
    const int pix = t >> 6;                           // pixel index h*128+w
    const int h   = pix >> 7;
    const int w   = pix & 127;

    // centered base grid: x=h-63.5, y=w-63.5, z=(d-31.5)*2
    const float bx = (float)h - 63.5f;
    const float by = (float)w - 63.5f;
    const float bz = ((float)d - 31.5f) * 2.0f;

    // q = T @ [bx,by,bz,1]  (T uniform across threads -> scalar loads)
    const float q0 = T[0]  * bx + T[1]  * by + T[2]  * bz + T[3];
    const float q1 = T[4]  * bx + T[5]  * by + T[6]  * bz + T[7];
    const float q2 = T[8]  * bx + T[9]  * by + T[10] * bz + T[11];
    const float qw = T[12] * bx + T[13] * by + T[14] * bz + T[15];

    // normalize by max|base coord| = 63.5 (same fp sequence as round 1)
    const float inv_max = 1.0f / 63.5f;
    const float nx = q0 * inv_max;
    const float ny = q1 * inv_max;
    const float nz = q2 * inv_max;

    // voxel-space coords, align_corners=True; x->Wm, y->Hm, z->Dm
    const float xf = (nx + 1.0f) * 0.5f * 127.0f;
    const float yf = (ny + 1.0f) * 0.5f * 127.0f;
    const float zf = (nz + 1.0f) * 0.5f * 127.0f;
    const float x0 = floorf(xf), y0 = floorf(yf), z0 = floorf(zf);
    const float fx = xf - x0, fy = yf - y0, fz = zf - z0;

    // wave-uniform skip: any corner of any lane inside the volume?
    const bool lane_touch = (xf >= -1.0f) && (x0 <= 127.0f)
                         && (yf >= -1.0f) && (y0 <= 127.0f)
                         && (zf >= -1.0f) && (z0 <= 127.0f);

    float m = 0.0f;
    if (__any(lane_touch)) {
        #pragma unroll
        for (int dz_ = 0; dz_ < 2; ++dz_) {
            #pragma unroll
            for (int dy_ = 0; dy_ < 2; ++dy_) {
                #pragma unroll
                for (int dx_ = 0; dx_ < 2; ++dx_) {
                    const float xi = x0 + (float)dx_;
                    const float yi = y0 + (float)dy_;
                    const float zi = z0 + (float)dz_;
                    const float wgt = (dx_ ? fx : 1.0f - fx)
                                    * (dy_ ? fy : 1.0f - fy)
                                    * (dz_ ? fz : 1.0f - fz);
                    const bool valid = (xi >= 0.0f) && (xi <= 127.0f)
                                    && (yi >= 0.0f) && (yi <= 127.0f)
                                    && (zi >= 0.0f) && (zi <= 127.0f);
                    const int xc = min(max((int)xi, 0), 127);
                    const int yc = min(max((int)yi, 0), 127);
                    const int zc = min(max((int)zi, 0), 127);
                    // bit (zc,yc,xc): u32 word ((zc*128+yc)*4 + xc/32), bit xc%32
                    const unsigned int word = bw[((zc << 7) + yc) * 4 + (xc >> 5)];
                    const bool bit = (word >> (xc & 31)) & 1u;
                    // identical partial sums to round 1 for binary vol:
                    m += (valid && bit) ? wgt : 0.0f;
                }
            }
        }
    }
    const float mask = (m != 0.0f) ? 1.0f : 0.0f;

    // field MLP: relu(q3 @ W1 + b1) @ W2 + b2, q3 = q/qw (qw == 1).
    // Skip entirely when the whole wave is masked out.
    float val = 0.0f;
    if (__any(mask != 0.0f)) {
        const float invw = 1.0f / qw;
        const float p0 = q0 * invw, p1 = q1 * invw, p2 = q2 * invw;
        float pot = b2[0];
        #pragma unroll 8
        for (int j = 0; j < HID; ++j) {
            float hj = p0 * W1[j] + p1 * W1[64 + j] + p2 * W1[128 + j] + b1[j];
            hj = fmaxf(hj, 0.0f);
            pot += hj * W2[j];
        }
        val = pot * mask;
    }

    // per-pixel reduction over the 64 depth lanes (one full wave)
    #pragma unroll
    for (int off = 32; off > 0; off >>= 1)
        val += __shfl_down(val, off);

    if (d == 0)
        out[pix] = val * 2.0f;   // * DZ
}

extern "C" void kernel_launch(void* const* d_in, const int* in_sizes, int n_in,
                              void* d_out, int out_size, void* d_ws, size_t ws_size,
                              hipStream_t stream) {
    const float* T   = (const float*)d_in[0];
    const float* vol = (const float*)d_in[1];
    const float* W1  = (const float*)d_in[2];
    const float* b1  = (const float*)d_in[3];
    const float* W2  = (const float*)d_in[4];
    const float* b2  = (const float*)d_in[5];
    float* out = (float*)d_out;

    unsigned long long* bits = (unsigned long long*)d_ws;   // 256 KB of d_ws

    // pack 2^21 voxels, 256 threads/block -> 8192 blocks
    pack_kernel<<<8192, 256, 0, stream>>>(vol, bits);

    const int n_points = NH * NW * ND;   // 1,048,576
    dmp_kernel<<<n_points / 256, 256, 0, stream>>>(
        T, (const unsigned int*)bits, W1, b1, W2, b2, out);
}